// Round 2
// baseline (151.656 us; speedup 1.0000x reference)
//
#include <hip/hip_runtime.h>
#include <hip/hip_bf16.h>

typedef __attribute__((ext_vector_type(8))) short bf16x8;
typedef __attribute__((ext_vector_type(8))) unsigned short u16x8;
typedef __attribute__((ext_vector_type(4))) float f32x4;

#define BM 128
#define NBLK (262144 / BM)   // 2048

// ws layout (bf16 elems, as u16):
//  [0      , 65536) : W1 chunk images: 8 chunks x 8192 elems; chunk kc, elem e: n=e/72, kl=e%72 -> W1[n][kc*64+kl], zero padded (n>=100 or kl>=64 -> 0)
//  [65536  , 73728) : Wtheta [64][128]  (row n<63, k<100 real else 0)
//  [73728  , 80896) : piT    [112][64]  (piT[c][l] = pi[l][c], c<100 else 0)
#define WS_WT 65536
#define WS_PI 73728
#define PREP_TOT 80896

__device__ __forceinline__ unsigned short bfc(float f) {
    union { float f; unsigned u; } v; v.f = f;
    unsigned r = (v.u + 0x7fffu + ((v.u >> 16) & 1u)) >> 16;   // RNE
    return (unsigned short)r;
}

// pair convert via hardware v_cvt_pk_bf16_f32 (compiler pattern-matches the cast pair)
__device__ __forceinline__ unsigned pack2(float a, float b) {
    float2 t; t.x = a; t.y = b;
    __hip_bfloat162 h2 = __float22bfloat162_rn(t);
    union { __hip_bfloat162 h; unsigned u; } v; v.h = h2;
    return v.u;
}

__device__ __forceinline__ unsigned short bf1(float a) {
    __hip_bfloat16 h = __float2bfloat16(a);
    union { __hip_bfloat16 h; unsigned short u; } v; v.h = h;
    return v.u;
}

#define GLLDS16(g, l) __builtin_amdgcn_global_load_lds( \
    (const __attribute__((address_space(1))) void*)(g), \
    (__attribute__((address_space(3))) void*)(l), 16, 0, 0)

__global__ void prep_kernel(const float* __restrict__ W1, const float* __restrict__ Wt,
                            const float* __restrict__ pi, unsigned short* __restrict__ ws) {
    int i = blockIdx.x * 256 + threadIdx.x;
    if (i >= PREP_TOT) return;
    float v = 0.0f;
    if (i < WS_WT) {
        int kc = i >> 13, e = i & 8191;
        int n = e / 72, kl = e - n * 72;
        if (n < 100 && kl < 64) v = W1[n * 512 + (kc << 6) + kl];
    } else if (i < WS_PI) {
        int e = i - WS_WT;
        int n = e >> 7, k = e & 127;
        if (n < 63 && k < 100) v = Wt[n * 100 + k];
    } else {
        int e = i - WS_PI;
        int c = e >> 6, l = e & 63;
        if (c < 100) v = pi[l * 100 + c];
    }
    ws[i] = bfc(v);
}

__global__ __launch_bounds__(256, 4) void treenet_kernel(
    const float* __restrict__ x, const float* __restrict__ b1,
    const float* __restrict__ bth, const unsigned short* __restrict__ ws,
    float* __restrict__ out)
{
    __shared__ __align__(16) unsigned char smem[34816];
    unsigned short* Xl  = (unsigned short*)smem;            // [128][72] bf16 (GEMM1)
    unsigned short* W1c = (unsigned short*)(smem + 18432);  // 8192 elems (GEMM1)
    unsigned short* Hl  = (unsigned short*)smem;            // [128][136] bf16 (GEMM2, aliases Xl+W1c)
    float*          Dl  = (float*)smem;                     // [128][65] f32  (aliases Hl)
    unsigned short* Mul = (unsigned short*)smem;            // [128][72] bf16 (aliases Dl, after barrier)

    const int tid  = threadIdx.x;
    const int lane = tid & 63;
    const int wv   = tid >> 6;                 // wave 0..3 -> rows wv*32..wv*32+31
    const int lm   = lane & 15;                // A-row / B-col / C-col component
    const int lk   = (lane >> 4) << 3;         // per-lane k offset (same map for A and B)
    const int crow = (wv << 5) + ((lane >> 4) << 2);  // C/D row base (m89 layout)
    const int row0 = blockIdx.x * BM;

    // ---------------- GEMM1: H = relu(X @ W1^T + b1), K=512 in 8 chunks ----------------
    float4 XA[4], XB[4];
    {   // prologue: load chunk 0 into regs
        const float* src = x + (size_t)row0 * 512;
        #pragma unroll
        for (int it = 0; it < 4; ++it) {
            int u = it * 256 + tid; int r = u >> 3, c8 = u & 7;
            const float* p = src + r * 512 + (c8 << 3);
            XA[it] = *(const float4*)p;
            XB[it] = *(const float4*)(p + 4);
        }
    }
    f32x4 acc[2][7] = {};

    for (int kc = 0; kc < 8; ++kc) {
        // issue this chunk's W1 image: global(ws) -> LDS direct (L2-resident, 16B/lane)
        {
            const unsigned short* src = ws + (kc << 13);
            #pragma unroll
            for (int it = 0; it < 4; ++it) {
                int u = it * 256 + tid;
                GLLDS16(src + (u << 3), W1c + (u << 3));
            }
        }
        // write staged X regs (cvt_pk to bf16) to LDS
        #pragma unroll
        for (int it = 0; it < 4; ++it) {
            int u = it * 256 + tid; int r = u >> 3, c8 = u & 7;
            uint4 pk;
            pk.x = pack2(XA[it].x, XA[it].y);
            pk.y = pack2(XA[it].z, XA[it].w);
            pk.z = pack2(XB[it].x, XB[it].y);
            pk.w = pack2(XB[it].z, XB[it].w);
            *(uint4*)(Xl + r * 72 + (c8 << 3)) = pk;
        }
        __syncthreads();   // vmcnt drain: W1c ready; lgkm: Xl visible
        // issue next chunk's global loads early (hide HBM latency under MFMA)
        if (kc < 7) {
            const float* src = x + (size_t)row0 * 512 + ((kc + 1) << 6);
            #pragma unroll
            for (int it = 0; it < 4; ++it) {
                int u = it * 256 + tid; int r = u >> 3, c8 = u & 7;
                const float* p = src + r * 512 + (c8 << 3);
                XA[it] = *(const float4*)p;
                XB[it] = *(const float4*)(p + 4);
            }
        }
        #pragma unroll
        for (int ks = 0; ks < 2; ++ks) {
            const int k0 = (ks << 5) + lk;
            bf16x8 af0 = *(const bf16x8*)(Xl + ((wv << 5) + lm) * 72 + k0);
            bf16x8 af1 = *(const bf16x8*)(Xl + ((wv << 5) + 16 + lm) * 72 + k0);
            #pragma unroll
            for (int fc = 0; fc < 7; ++fc) {
                bf16x8 bf = *(const bf16x8*)(W1c + ((fc << 4) + lm) * 72 + k0);
                acc[0][fc] = __builtin_amdgcn_mfma_f32_16x16x32_bf16(af0, bf, acc[0][fc], 0, 0, 0);
                acc[1][fc] = __builtin_amdgcn_mfma_f32_16x16x32_bf16(af1, bf, acc[1][fc], 0, 0, 0);
            }
        }
        __syncthreads();
    }

    // epilogue: bias + relu -> H (bf16) in LDS, K-padded to 128
    #pragma unroll
    for (int fc = 0; fc < 7; ++fc) {
        int c = (fc << 4) + lm;
        float bb = (c < 100) ? b1[c] : 0.0f;
        #pragma unroll
        for (int fr = 0; fr < 2; ++fr)
            #pragma unroll
            for (int r = 0; r < 4; ++r) {
                float h = acc[fr][fc][r] + bb;
                h = h > 0.0f ? h : 0.0f;
                Hl[(crow + (fr << 4) + r) * 136 + c] = bf1(h);
            }
    }
    {   // zero-fill H[:,112..127]
        u16x8 z = {0,0,0,0,0,0,0,0};
        *(u16x8*)(Hl + (tid >> 1) * 136 + 112 + ((tid & 1) << 3)) = z;
    }
    __syncthreads();

    // ---------------- GEMM2: D = sigmoid(H @ Wtheta^T + bth), K=128 ----------------
    f32x4 acc2[2][4] = {};
    const unsigned short* Wt = ws + WS_WT;
    #pragma unroll
    for (int ks = 0; ks < 4; ++ks) {
        const int k0 = (ks << 5) + lk;
        bf16x8 af0 = *(const bf16x8*)(Hl + ((wv << 5) + lm) * 136 + k0);
        bf16x8 af1 = *(const bf16x8*)(Hl + ((wv << 5) + 16 + lm) * 136 + k0);
        #pragma unroll
        for (int fc = 0; fc < 4; ++fc) {
            bf16x8 bf = *(const bf16x8*)(Wt + ((fc << 4) + lm) * 128 + k0);
            acc2[0][fc] = __builtin_amdgcn_mfma_f32_16x16x32_bf16(af0, bf, acc2[0][fc], 0, 0, 0);
            acc2[1][fc] = __builtin_amdgcn_mfma_f32_16x16x32_bf16(af1, bf, acc2[1][fc], 0, 0, 0);
        }
    }
    __syncthreads();   // done reading Hl; Dl aliases it
    #pragma unroll
    for (int fc = 0; fc < 4; ++fc) {
        int c = (fc << 4) + lm;
        float bb = (c < 63) ? bth[c] : 0.0f;
        #pragma unroll
        for (int fr = 0; fr < 2; ++fr)
            #pragma unroll
            for (int r = 0; r < 4; ++r) {
                float t = acc2[fr][fc][r] + bb;
                float d = 1.0f / (1.0f + __expf(-t));
                Dl[(crow + (fr << 4) + r) * 65 + c] = d;
            }
    }
    __syncthreads();

    // ---------------- tree products: mu (2 threads per row, 32 leaves each) ----------------
    {
        const int row = tid >> 1, p = tid & 1;
        const float* Dr = Dl + row * 65;
        float d0 = Dr[0];
        float m1 = p ? (1.0f - d0) : d0;
        float dA = Dr[1 + p];
        float m2[2]; m2[0] = m1 * dA; m2[1] = m1 * (1.0f - dA);
        float m4[4];
        #pragma unroll
        for (int i = 0; i < 2; ++i) { float d = Dr[3 + (p << 1) + i];  m4[2*i] = m2[i]*d;  m4[2*i+1] = m2[i]*(1.0f-d); }
        float m8[8];
        #pragma unroll
        for (int i = 0; i < 4; ++i) { float d = Dr[7 + (p << 2) + i];  m8[2*i] = m4[i]*d;  m8[2*i+1] = m4[i]*(1.0f-d); }
        float m16[16];
        #pragma unroll
        for (int i = 0; i < 8; ++i) { float d = Dr[15 + (p << 3) + i]; m16[2*i] = m8[i]*d; m16[2*i+1] = m8[i]*(1.0f-d); }
        float dleaf[16];
        #pragma unroll
        for (int i = 0; i < 16; ++i) dleaf[i] = Dr[31 + (p << 4) + i];
        __syncthreads();   // all reads of Dl complete; Mul may now alias it
        unsigned short* Mr = Mul + row * 72 + (p << 5);
        #pragma unroll
        for (int i = 0; i < 16; ++i) {
            float a = m16[i] * dleaf[i], b = m16[i] * (1.0f - dleaf[i]);
            *(unsigned*)(Mr + (i << 1)) = pack2(a, b);
        }
    }
    __syncthreads();

    // ---------------- GEMM3: out = mu @ pi, K=64 ----------------
    f32x4 acc3[2][7] = {};
    const unsigned short* piT = ws + WS_PI;
    #pragma unroll
    for (int ks = 0; ks < 2; ++ks) {
        const int k0 = (ks << 5) + lk;
        bf16x8 af0 = *(const bf16x8*)(Mul + ((wv << 5) + lm) * 72 + k0);
        bf16x8 af1 = *(const bf16x8*)(Mul + ((wv << 5) + 16 + lm) * 72 + k0);
        #pragma unroll
        for (int fc = 0; fc < 7; ++fc) {
            bf16x8 bf = *(const bf16x8*)(piT + ((fc << 4) + lm) * 64 + k0);
            acc3[0][fc] = __builtin_amdgcn_mfma_f32_16x16x32_bf16(af0, bf, acc3[0][fc], 0, 0, 0);
            acc3[1][fc] = __builtin_amdgcn_mfma_f32_16x16x32_bf16(af1, bf, acc3[1][fc], 0, 0, 0);
        }
    }
    #pragma unroll
    for (int fc = 0; fc < 7; ++fc) {
        int c = (fc << 4) + lm;
        if (c < 100) {
            #pragma unroll
            for (int fr = 0; fr < 2; ++fr)
                #pragma unroll
                for (int r = 0; r < 4; ++r)
                    out[(size_t)(row0 + crow + (fr << 4) + r) * 100 + c] = acc3[fr][fc][r];
        }
    }
}

extern "C" void kernel_launch(void* const* d_in, const int* in_sizes, int n_in,
                              void* d_out, int out_size, void* d_ws, size_t ws_size,
                              hipStream_t stream) {
    const float* x   = (const float*)d_in[0];
    const float* W1  = (const float*)d_in[1];
    const float* b1  = (const float*)d_in[2];
    const float* Wt  = (const float*)d_in[3];
    const float* bth = (const float*)d_in[4];
    const float* pi  = (const float*)d_in[5];
    unsigned short* ws = (unsigned short*)d_ws;

    prep_kernel<<<(PREP_TOT + 255) / 256, 256, 0, stream>>>(W1, Wt, pi, ws);
    treenet_kernel<<<NBLK, 256, 0, stream>>>(x, b1, bth, ws, (float*)d_out);
}

// Round 3
// 146.625 us; speedup vs baseline: 1.0343x; 1.0343x over previous
//
#include <hip/hip_runtime.h>
#include <hip/hip_bf16.h>

typedef __attribute__((ext_vector_type(8))) short bf16x8;
typedef __attribute__((ext_vector_type(8))) unsigned short u16x8;
typedef __attribute__((ext_vector_type(4))) float f32x4;

#define BM 128
#define NBLK (262144 / BM)   // 2048

// ws layout (bf16 elems, as u16):
//  [0      , 65536) : W1 chunk images: 8 chunks x 8192 elems; chunk kc, elem e: n=e/72, kl=e%72 -> W1[n][kc*64+kl], zero padded
//  [65536  , 73728) : Wtheta [64][128]
//  [73728  , 80896) : piT    [112][64]
#define WS_WT 65536
#define WS_PI 73728
#define PREP_TOT 80896

#define MEMFENCE asm volatile("" ::: "memory")
#define WAIT_LGKM0 asm volatile("s_waitcnt lgkmcnt(0)" ::: "memory")
#define WAIT_VM8   asm volatile("s_waitcnt vmcnt(8)" ::: "memory")
#define WAIT_VM0   asm volatile("s_waitcnt vmcnt(0)" ::: "memory")
#define SBAR do { __builtin_amdgcn_sched_barrier(0); __builtin_amdgcn_s_barrier(); __builtin_amdgcn_sched_barrier(0); } while (0)

__device__ __forceinline__ unsigned short bfc(float f) {
    union { float f; unsigned u; } v; v.f = f;
    unsigned r = (v.u + 0x7fffu + ((v.u >> 16) & 1u)) >> 16;   // RNE
    return (unsigned short)r;
}

__device__ __forceinline__ unsigned pack2(float a, float b) {
    float2 t; t.x = a; t.y = b;
    __hip_bfloat162 h2 = __float22bfloat162_rn(t);
    union { __hip_bfloat162 h; unsigned u; } v; v.h = h2;
    return v.u;
}

__device__ __forceinline__ unsigned short bf1(float a) {
    __hip_bfloat16 h = __float2bfloat16(a);
    union { __hip_bfloat16 h; unsigned short u; } v; v.h = h;
    return v.u;
}

#define GLLDS16(g, l) __builtin_amdgcn_global_load_lds( \
    (const __attribute__((address_space(1))) void*)(g), \
    (__attribute__((address_space(3))) void*)(l), 16, 0, 0)

__global__ void prep_kernel(const float* __restrict__ W1, const float* __restrict__ Wt,
                            const float* __restrict__ pi, unsigned short* __restrict__ ws) {
    int i = blockIdx.x * 256 + threadIdx.x;
    if (i >= PREP_TOT) return;
    float v = 0.0f;
    if (i < WS_WT) {
        int kc = i >> 13, e = i & 8191;
        int n = e / 72, kl = e - n * 72;
        if (n < 100 && kl < 64) v = W1[n * 512 + (kc << 6) + kl];
    } else if (i < WS_PI) {
        int e = i - WS_WT;
        int n = e >> 7, k = e & 127;
        if (n < 63 && k < 100) v = Wt[n * 100 + k];
    } else {
        int e = i - WS_PI;
        int c = e >> 6, l = e & 63;
        if (c < 100) v = pi[l * 100 + c];
    }
    ws[i] = bfc(v);
}

__global__ __launch_bounds__(256, 4) void treenet_kernel(
    const float* __restrict__ x, const float* __restrict__ b1,
    const float* __restrict__ bth, const unsigned short* __restrict__ ws,
    float* __restrict__ out)
{
    __shared__ __align__(16) unsigned char smem[34816];
    unsigned short* Xl  = (unsigned short*)smem;            // [128][72] bf16 (GEMM1)
    unsigned short* W1c = (unsigned short*)(smem + 18432);  // 8192 elems (GEMM1)
    unsigned short* Hl  = (unsigned short*)smem;            // [128][136] bf16 (GEMM2, aliases)
    float*          Dl  = (float*)smem;                     // [128][65] f32  (aliases Hl)
    unsigned short* Mul = (unsigned short*)smem;            // [128][72] bf16 (aliases Dl)

    const int tid  = threadIdx.x;
    const int lane = tid & 63;
    const int wv   = tid >> 6;
    const int lm   = lane & 15;
    const int lk   = (lane >> 4) << 3;
    const int crow = (wv << 5) + ((lane >> 4) << 2);
    const int row0 = blockIdx.x * BM;

    // ---------------- GEMM1: H = relu(X @ W1^T + b1), K=512 in 8 chunks ----------------
    float4 XA[4], XB[4];
    {   // prologue: load chunk 0 into regs
        const float* src = x + (size_t)row0 * 512;
        #pragma unroll
        for (int it = 0; it < 4; ++it) {
            int u = it * 256 + tid; int r = u >> 3, c8 = u & 7;
            const float* p = src + r * 512 + (c8 << 3);
            XA[it] = *(const float4*)p;
            XB[it] = *(const float4*)(p + 4);
        }
    }
    f32x4 acc[2][7] = {};

    for (int kc = 0; kc < 8; ++kc) {
        // 1. issue this chunk's W1 image: global(ws, L2) -> LDS direct (vmcnt +2)
        {
            const unsigned short* src = ws + (kc << 13);
            #pragma unroll
            for (int it = 0; it < 4; ++it) {
                int u = it * 256 + tid;
                GLLDS16(src + (u << 3), W1c + (u << 3));
            }
        }
        MEMFENCE;   // keep gllds issued before everything below
        // 2. stage X regs (cvt_pk) -> LDS
        #pragma unroll
        for (int it = 0; it < 4; ++it) {
            int u = it * 256 + tid; int r = u >> 3, c8 = u & 7;
            uint4 pk;
            pk.x = pack2(XA[it].x, XA[it].y);
            pk.y = pack2(XA[it].z, XA[it].w);
            pk.z = pack2(XB[it].x, XB[it].y);
            pk.w = pack2(XB[it].z, XB[it].w);
            *(uint4*)(Xl + r * 72 + (c8 << 3)) = pk;
        }
        // 3. issue next chunk's X loads NOW (vmcnt +8) — they stay in flight across
        //    both barriers and the MFMA phase (counted vmcnt, never drained)
        if (kc < 7) {
            const float* src = x + (size_t)row0 * 512 + ((kc + 1) << 6);
            #pragma unroll
            for (int it = 0; it < 4; ++it) {
                int u = it * 256 + tid; int r = u >> 3, c8 = u & 7;
                const float* p = src + r * 512 + (c8 << 3);
                XA[it] = *(const float4*)p;
                XB[it] = *(const float4*)(p + 4);
            }
            WAIT_LGKM0;           // my ds_writes visible
            WAIT_VM8;             // my 2 gllds done; 8 X loads stay in flight
        } else {
            WAIT_LGKM0;
            WAIT_VM0;             // last chunk: drain gllds (no prefetch outstanding)
        }
        SBAR;   // all waves staged
        // 4. MFMA phase
        #pragma unroll
        for (int ks = 0; ks < 2; ++ks) {
            const int k0 = (ks << 5) + lk;
            bf16x8 af0 = *(const bf16x8*)(Xl + ((wv << 5) + lm) * 72 + k0);
            bf16x8 af1 = *(const bf16x8*)(Xl + ((wv << 5) + 16 + lm) * 72 + k0);
            #pragma unroll
            for (int fc = 0; fc < 7; ++fc) {
                bf16x8 bf = *(const bf16x8*)(W1c + ((fc << 4) + lm) * 72 + k0);
                acc[0][fc] = __builtin_amdgcn_mfma_f32_16x16x32_bf16(af0, bf, acc[0][fc], 0, 0, 0);
                acc[1][fc] = __builtin_amdgcn_mfma_f32_16x16x32_bf16(af1, bf, acc[1][fc], 0, 0, 0);
            }
        }
        WAIT_LGKM0;   // my LDS reads complete (frags in regs)
        SBAR;         // all waves done reading; next stage may overwrite (no vm drain)
    }

    // epilogue: bias + relu -> H (bf16) in LDS, K-padded to 128
    #pragma unroll
    for (int fc = 0; fc < 7; ++fc) {
        int c = (fc << 4) + lm;
        float bb = (c < 100) ? b1[c] : 0.0f;
        #pragma unroll
        for (int fr = 0; fr < 2; ++fr)
            #pragma unroll
            for (int r = 0; r < 4; ++r) {
                float h = acc[fr][fc][r] + bb;
                h = h > 0.0f ? h : 0.0f;
                Hl[(crow + (fr << 4) + r) * 136 + c] = bf1(h);
            }
    }
    {   // zero-fill H[:,112..127]
        u16x8 z = {0,0,0,0,0,0,0,0};
        *(u16x8*)(Hl + (tid >> 1) * 136 + 112 + ((tid & 1) << 3)) = z;
    }
    __syncthreads();

    // ---------------- GEMM2: D = sigmoid(H @ Wtheta^T + bth), K=128 ----------------
    f32x4 acc2[2][4] = {};
    const unsigned short* Wt = ws + WS_WT;
    #pragma unroll
    for (int ks = 0; ks < 4; ++ks) {
        const int k0 = (ks << 5) + lk;
        bf16x8 af0 = *(const bf16x8*)(Hl + ((wv << 5) + lm) * 136 + k0);
        bf16x8 af1 = *(const bf16x8*)(Hl + ((wv << 5) + 16 + lm) * 136 + k0);
        #pragma unroll
        for (int fc = 0; fc < 4; ++fc) {
            bf16x8 bf = *(const bf16x8*)(Wt + ((fc << 4) + lm) * 128 + k0);
            acc2[0][fc] = __builtin_amdgcn_mfma_f32_16x16x32_bf16(af0, bf, acc2[0][fc], 0, 0, 0);
            acc2[1][fc] = __builtin_amdgcn_mfma_f32_16x16x32_bf16(af1, bf, acc2[1][fc], 0, 0, 0);
        }
    }
    __syncthreads();   // done reading Hl; Dl aliases it
    #pragma unroll
    for (int fc = 0; fc < 4; ++fc) {
        int c = (fc << 4) + lm;
        float bb = (c < 63) ? bth[c] : 0.0f;
        #pragma unroll
        for (int fr = 0; fr < 2; ++fr)
            #pragma unroll
            for (int r = 0; r < 4; ++r) {
                float t = acc2[fr][fc][r] + bb;
                float d = 1.0f / (1.0f + __expf(-t));
                Dl[(crow + (fr << 4) + r) * 65 + c] = d;
            }
    }
    __syncthreads();

    // ---------------- tree products: mu (2 threads per row, 32 leaves each) ----------------
    {
        const int row = tid >> 1, p = tid & 1;
        const float* Dr = Dl + row * 65;
        float d0 = Dr[0];
        float m1 = p ? (1.0f - d0) : d0;
        float dA = Dr[1 + p];
        float m2[2]; m2[0] = m1 * dA; m2[1] = m1 * (1.0f - dA);
        float m4[4];
        #pragma unroll
        for (int i = 0; i < 2; ++i) { float d = Dr[3 + (p << 1) + i];  m4[2*i] = m2[i]*d;  m4[2*i+1] = m2[i]*(1.0f-d); }
        float m8[8];
        #pragma unroll
        for (int i = 0; i < 4; ++i) { float d = Dr[7 + (p << 2) + i];  m8[2*i] = m4[i]*d;  m8[2*i+1] = m4[i]*(1.0f-d); }
        float m16[16];
        #pragma unroll
        for (int i = 0; i < 8; ++i) { float d = Dr[15 + (p << 3) + i]; m16[2*i] = m8[i]*d; m16[2*i+1] = m8[i]*(1.0f-d); }
        float dleaf[16];
        #pragma unroll
        for (int i = 0; i < 16; ++i) dleaf[i] = Dr[31 + (p << 4) + i];
        __syncthreads();   // all reads of Dl complete; Mul may now alias it
        unsigned short* Mr = Mul + row * 72 + (p << 5);
        #pragma unroll
        for (int i = 0; i < 16; ++i) {
            float a = m16[i] * dleaf[i], b = m16[i] * (1.0f - dleaf[i]);
            *(unsigned*)(Mr + (i << 1)) = pack2(a, b);
        }
    }
    __syncthreads();

    // ---------------- GEMM3: out = mu @ pi, K=64 ----------------
    f32x4 acc3[2][7] = {};
    const unsigned short* piT = ws + WS_PI;
    #pragma unroll
    for (int ks = 0; ks < 2; ++ks) {
        const int k0 = (ks << 5) + lk;
        bf16x8 af0 = *(const bf16x8*)(Mul + ((wv << 5) + lm) * 72 + k0);
        bf16x8 af1 = *(const bf16x8*)(Mul + ((wv << 5) + 16 + lm) * 72 + k0);
        #pragma unroll
        for (int fc = 0; fc < 7; ++fc) {
            bf16x8 bf = *(const bf16x8*)(piT + ((fc << 4) + lm) * 64 + k0);
            acc3[0][fc] = __builtin_amdgcn_mfma_f32_16x16x32_bf16(af0, bf, acc3[0][fc], 0, 0, 0);
            acc3[1][fc] = __builtin_amdgcn_mfma_f32_16x16x32_bf16(af1, bf, acc3[1][fc], 0, 0, 0);
        }
    }
    #pragma unroll
    for (int fc = 0; fc < 7; ++fc) {
        int c = (fc << 4) + lm;
        if (c < 100) {
            #pragma unroll
            for (int fr = 0; fr < 2; ++fr)
                #pragma unroll
                for (int r = 0; r < 4; ++r)
                    out[(size_t)(row0 + crow + (fr << 4) + r) * 100 + c] = acc3[fr][fc][r];
        }
    }
}

extern "C" void kernel_launch(void* const* d_in, const int* in_sizes, int n_in,
                              void* d_out, int out_size, void* d_ws, size_t ws_size,
                              hipStream_t stream) {
    const float* x   = (const float*)d_in[0];
    const float* W1  = (const float*)d_in[1];
    const float* b1  = (const float*)d_in[2];
    const float* Wt  = (const float*)d_in[3];
    const float* bth = (const float*)d_in[4];
    const float* pi  = (const float*)d_in[5];
    unsigned short* ws = (unsigned short*)d_ws;

    prep_kernel<<<(PREP_TOT + 255) / 256, 256, 0, stream>>>(W1, Wt, pi, ws);
    treenet_kernel<<<NBLK, 256, 0, stream>>>(x, b1, bth, ws, (float*)d_out);
}